// Round 1
// baseline (1045.300 us; speedup 1.0000x reference)
//
#include <hip/hip_runtime.h>
#include <hip/hip_bf16.h>

#define DMODEL 256
#define HEADS 8
#define EHEAD 32
#define BATCH 32
#define NB 4
#define LT 256
#define LC 128
#define SCALE_F 0.17677669529663687f  // 1/sqrt(32)

// ---------------------------------------------------------------------------
// Generic z-batched GEMM: C[z] = A[z] @ W[z] + bias[z]
// A: [M, 256] row-major, W: [256, 256] row-major, C: [M, 256].
// M must be a multiple of 64 (all our cases: 8192, 4096, 128).
// 64x64 tile per workgroup, 256 threads, 4x4 micro-tile per thread.
// ---------------------------------------------------------------------------
__global__ __launch_bounds__(256) void gemm_bias(
    const float* __restrict__ A, const float* __restrict__ W,
    const float* __restrict__ bias, float* __restrict__ C,
    long long sA, long long sW, long long sBias, long long sC)
{
    const int z = blockIdx.z;
    A    += (long long)z * sA;
    W    += (long long)z * sW;
    bias += (long long)z * sBias;
    C    += (long long)z * sC;

    const int bm  = blockIdx.y * 64;
    const int bn  = blockIdx.x * 64;
    const int tid = threadIdx.x;
    const int tx  = tid & 15;   // n direction (4 cols each)
    const int ty  = tid >> 4;   // m direction (4 rows each)

    __shared__ float As[16][68];  // [k][m], pad 68 keeps float4 align, breaks pow2
    __shared__ float Bs[16][68];  // [k][n]

    float acc[4][4] = {};

    for (int k0 = 0; k0 < DMODEL; k0 += 16) {
        // Load A tile (64 rows x 16 k) -> As[k][m]
        #pragma unroll
        for (int r = 0; r < 4; ++r) {
            int t  = tid + r * 256;
            int m  = t >> 4;
            int kk = t & 15;
            As[kk][m] = A[(long long)(bm + m) * DMODEL + (k0 + kk)];
        }
        // Load W tile (16 k x 64 n) -> Bs[k][n]
        #pragma unroll
        for (int r = 0; r < 4; ++r) {
            int t  = tid + r * 256;
            int kk = t >> 6;
            int n  = t & 63;
            Bs[kk][n] = W[(long long)(k0 + kk) * DMODEL + (bn + n)];
        }
        __syncthreads();

        #pragma unroll
        for (int kk = 0; kk < 16; ++kk) {
            float4 a4 = *(const float4*)&As[kk][ty * 4];
            float4 b4 = *(const float4*)&Bs[kk][tx * 4];
            float a[4] = {a4.x, a4.y, a4.z, a4.w};
            float b[4] = {b4.x, b4.y, b4.z, b4.w};
            #pragma unroll
            for (int i = 0; i < 4; ++i)
                #pragma unroll
                for (int j = 0; j < 4; ++j)
                    acc[i][j] = fmaf(a[i], b[j], acc[i][j]);
        }
        __syncthreads();
    }

    #pragma unroll
    for (int i = 0; i < 4; ++i) {
        long long m = bm + ty * 4 + i;
        #pragma unroll
        for (int j = 0; j < 4; ++j) {
            int n = bn + tx * 4 + j;
            C[m * DMODEL + n] = acc[i][j] + bias[n];
        }
    }
}

// ---------------------------------------------------------------------------
// Intra-block multi-head attention.
// Q/K/V: [nb*B*L, 256] rows; head h occupies cols h*32 .. h*32+31.
// Grid: (HEADS, nb*B); block: L threads (one per query row).
// Dynamic LDS: K and V head-slices, 2 * L * 32 floats.
// ---------------------------------------------------------------------------
__global__ void attn_intra(const float* __restrict__ Q, const float* __restrict__ K,
                           const float* __restrict__ V, float* __restrict__ O, int L)
{
    extern __shared__ float lds[];
    float* Ks = lds;                    // [L][32]
    float* Vs = lds + (size_t)L * EHEAD;

    const int h = blockIdx.x;
    const long long base = (long long)blockIdx.y * L;
    const int tid = threadIdx.x;

    for (int idx = tid; idx < L * 8; idx += blockDim.x) {
        int s  = idx >> 3;
        int e4 = idx & 7;
        *(float4*)&Ks[s * EHEAD + e4 * 4] =
            *(const float4*)&K[(base + s) * DMODEL + h * EHEAD + e4 * 4];
        *(float4*)&Vs[s * EHEAD + e4 * 4] =
            *(const float4*)&V[(base + s) * DMODEL + h * EHEAD + e4 * 4];
    }
    __syncthreads();

    float4 q[8];
    #pragma unroll
    for (int i = 0; i < 8; ++i)
        q[i] = *(const float4*)&Q[(base + tid) * DMODEL + h * EHEAD + i * 4];

    float4 acc[8] = {};
    float m = -1e30f, lsum = 0.f;

    for (int s = 0; s < L; ++s) {
        float sc = 0.f;
        #pragma unroll
        for (int i = 0; i < 8; ++i) {
            float4 k4 = *(const float4*)&Ks[s * EHEAD + i * 4];
            sc = fmaf(q[i].x, k4.x, sc);
            sc = fmaf(q[i].y, k4.y, sc);
            sc = fmaf(q[i].z, k4.z, sc);
            sc = fmaf(q[i].w, k4.w, sc);
        }
        sc *= SCALE_F;
        float mn = fmaxf(m, sc);
        float r  = __expf(m - mn);   // == 1 when max unchanged; == 0 on first iter
        float p  = __expf(sc - mn);
        lsum = lsum * r + p;
        #pragma unroll
        for (int i = 0; i < 8; ++i) {
            float4 v4 = *(const float4*)&Vs[s * EHEAD + i * 4];
            acc[i].x = fmaf(acc[i].x, r, p * v4.x);
            acc[i].y = fmaf(acc[i].y, r, p * v4.y);
            acc[i].z = fmaf(acc[i].z, r, p * v4.z);
            acc[i].w = fmaf(acc[i].w, r, p * v4.w);
        }
        m = mn;
    }

    const float inv = 1.f / lsum;
    #pragma unroll
    for (int i = 0; i < 8; ++i) {
        float4 o4;
        o4.x = acc[i].x * inv; o4.y = acc[i].y * inv;
        o4.z = acc[i].z * inv; o4.w = acc[i].w * inv;
        *(float4*)&O[(base + tid) * DMODEL + h * EHEAD + i * 4] = o4;
    }
}

// ---------------------------------------------------------------------------
// routers[b*4 + i][d] = x_intra[i][b][L-1][d]
// ---------------------------------------------------------------------------
__global__ void gather_routers(const float* __restrict__ xi, float* __restrict__ rt, int L)
{
    int t = blockIdx.x * blockDim.x + threadIdx.x;  // 0 .. 32767
    int d = t & 255;
    int r = t >> 8;       // b*4 + i
    int i = r & 3;
    int b = r >> 2;
    rt[(long long)r * DMODEL + d] =
        xi[(((long long)i * BATCH + b) * L + (L - 1)) * DMODEL + d];
}

// ---------------------------------------------------------------------------
// Tiny inter attention over 4 router tokens. 1024 threads total: (b, h, l).
// ---------------------------------------------------------------------------
__global__ void inter_attn(const float* __restrict__ RQ, const float* __restrict__ RK,
                           const float* __restrict__ RV, float* __restrict__ RA)
{
    int t = blockIdx.x * blockDim.x + threadIdx.x;  // 0 .. 1023
    int l = t & 3;
    int h = (t >> 2) & 7;
    int b = t >> 5;

    float q[EHEAD];
    #pragma unroll
    for (int e = 0; e < EHEAD; ++e)
        q[e] = RQ[((long long)b * 4 + l) * DMODEL + h * EHEAD + e];

    float sc[4];
    float m = -1e30f;
    #pragma unroll
    for (int s = 0; s < 4; ++s) {
        float d = 0.f;
        #pragma unroll
        for (int e = 0; e < EHEAD; ++e)
            d = fmaf(q[e], RK[((long long)b * 4 + s) * DMODEL + h * EHEAD + e], d);
        sc[s] = d * SCALE_F;
        m = fmaxf(m, sc[s]);
    }
    float lsum = 0.f;
    #pragma unroll
    for (int s = 0; s < 4; ++s) { sc[s] = __expf(sc[s] - m); lsum += sc[s]; }
    const float inv = 1.f / lsum;

    #pragma unroll
    for (int e = 0; e < EHEAD; ++e) {
        float a = 0.f;
        #pragma unroll
        for (int s = 0; s < 4; ++s)
            a = fmaf(sc[s], RV[((long long)b * 4 + s) * DMODEL + h * EHEAD + e], a);
        RA[((long long)b * 4 + l) * DMODEL + h * EHEAD + e] = a * inv;
    }
}

// ---------------------------------------------------------------------------
// out[i][b][L-1][d] = ro[b*4 + i][d]
// ---------------------------------------------------------------------------
__global__ void scatter_routers(const float* __restrict__ ro, float* __restrict__ xi, int L)
{
    int t = blockIdx.x * blockDim.x + threadIdx.x;  // 0 .. 32767
    int d = t & 255;
    int r = t >> 8;
    int i = r & 3;
    int b = r >> 2;
    xi[(((long long)i * BATCH + b) * L + (L - 1)) * DMODEL + d] =
        ro[(long long)r * DMODEL + d];
}

// ---------------------------------------------------------------------------
// One branch (intra + router inter attention)
// ---------------------------------------------------------------------------
static void run_branch(const float* x,
    const float* Wq, const float* bq, const float* Wk, const float* bk,
    const float* Wv, const float* bv, const float* Wo, const float* bo,
    const float* Wqi, const float* bqi, const float* Wki, const float* bki,
    const float* Wvi, const float* bvi, const float* Woi, const float* boi,
    float* out, int L,
    float* Qb, float* Kb, float* Vb, float* AO,
    float* RT, float* RQ, float* RK, float* RV, float* RA, float* RO,
    hipStream_t stream)
{
    const int M = BATCH * L;                 // rows per nb-block
    const long long sX = (long long)M * DMODEL;
    const long long sW = (long long)DMODEL * DMODEL;

    dim3 gProj(DMODEL / 64, M / 64, NB);
    gemm_bias<<<gProj, 256, 0, stream>>>(x, Wq, bq, Qb, sX, sW, DMODEL, sX);
    gemm_bias<<<gProj, 256, 0, stream>>>(x, Wk, bk, Kb, sX, sW, DMODEL, sX);
    gemm_bias<<<gProj, 256, 0, stream>>>(x, Wv, bv, Vb, sX, sW, DMODEL, sX);

    dim3 gAtt(HEADS, NB * BATCH);
    size_t shmem = (size_t)L * EHEAD * 2 * sizeof(float);
    attn_intra<<<gAtt, L, shmem, stream>>>(Qb, Kb, Vb, AO, L);

    gemm_bias<<<gProj, 256, 0, stream>>>(AO, Wo, bo, out, sX, sW, DMODEL, sX);

    gather_routers<<<128, 256, 0, stream>>>(out, RT, L);

    dim3 gI(DMODEL / 64, 128 / 64, 1);
    gemm_bias<<<gI, 256, 0, stream>>>(RT, Wqi, bqi, RQ, 0, 0, 0, 0);
    gemm_bias<<<gI, 256, 0, stream>>>(RT, Wki, bki, RK, 0, 0, 0, 0);
    gemm_bias<<<gI, 256, 0, stream>>>(RT, Wvi, bvi, RV, 0, 0, 0, 0);

    inter_attn<<<4, 256, 0, stream>>>(RQ, RK, RV, RA);

    gemm_bias<<<gI, 256, 0, stream>>>(RA, Woi, boi, RO, 0, 0, 0, 0);

    scatter_routers<<<128, 256, 0, stream>>>(RO, out, L);
}

// ---------------------------------------------------------------------------
extern "C" void kernel_launch(void* const* d_in, const int* in_sizes, int n_in,
                              void* d_out, int out_size, void* d_ws, size_t ws_size,
                              hipStream_t stream)
{
    const float* x_t  = (const float*)d_in[0];
    const float* x_c  = (const float*)d_in[1];
    const float* Wq_t = (const float*)d_in[2];  const float* bq_t = (const float*)d_in[3];
    const float* Wk_t = (const float*)d_in[4];  const float* bk_t = (const float*)d_in[5];
    const float* Wv_t = (const float*)d_in[6];  const float* bv_t = (const float*)d_in[7];
    const float* Wo_t = (const float*)d_in[8];  const float* bo_t = (const float*)d_in[9];
    const float* Wq_c = (const float*)d_in[10]; const float* bq_c = (const float*)d_in[11];
    const float* Wk_c = (const float*)d_in[12]; const float* bk_c = (const float*)d_in[13];
    const float* Wv_c = (const float*)d_in[14]; const float* bv_c = (const float*)d_in[15];
    const float* Wo_c = (const float*)d_in[16]; const float* bo_c = (const float*)d_in[17];
    const float* Wq_it = (const float*)d_in[18]; const float* bq_it = (const float*)d_in[19];
    const float* Wk_it = (const float*)d_in[20]; const float* bk_it = (const float*)d_in[21];
    const float* Wv_it = (const float*)d_in[22]; const float* bv_it = (const float*)d_in[23];
    const float* Wo_it = (const float*)d_in[24]; const float* bo_it = (const float*)d_in[25];
    const float* Wq_ic = (const float*)d_in[26]; const float* bq_ic = (const float*)d_in[27];
    const float* Wk_ic = (const float*)d_in[28]; const float* bk_ic = (const float*)d_in[29];
    const float* Wv_ic = (const float*)d_in[30]; const float* bv_ic = (const float*)d_in[31];
    const float* Wo_ic = (const float*)d_in[32]; const float* bo_ic = (const float*)d_in[33];

    float* out = (float*)d_out;
    float* ws  = (float*)d_ws;

    // Workspace layout (sized for the larger t branch; c reuses the same buffers)
    const size_t QKV = (size_t)NB * BATCH * LT * DMODEL;  // 8,388,608 floats
    float* Qb = ws;
    float* Kb = Qb + QKV;
    float* Vb = Kb + QKV;
    float* AO = Vb + QKV;
    float* RT = AO + QKV;
    float* RQ = RT + 128 * DMODEL;
    float* RK = RQ + 128 * DMODEL;
    float* RV = RK + 128 * DMODEL;
    float* RA = RV + 128 * DMODEL;
    float* RO = RA + 128 * DMODEL;

    // t branch -> out[0 .. 8388608)
    run_branch(x_t, Wq_t, bq_t, Wk_t, bk_t, Wv_t, bv_t, Wo_t, bo_t,
               Wq_it, bq_it, Wk_it, bk_it, Wv_it, bv_it, Wo_it, bo_it,
               out, LT, Qb, Kb, Vb, AO, RT, RQ, RK, RV, RA, RO, stream);

    // c branch -> out[8388608 .. 12582912)
    float* out_c = out + (size_t)NB * BATCH * LT * DMODEL;
    run_branch(x_c, Wq_c, bq_c, Wk_c, bk_c, Wv_c, bv_c, Wo_c, bo_c,
               Wq_ic, bq_ic, Wk_ic, bk_ic, Wv_ic, bv_ic, Wo_ic, bo_ic,
               out_c, LC, Qb, Kb, Vb, AO, RT, RQ, RK, RV, RA, RO, stream);
}

// Round 2
// 702.815 us; speedup vs baseline: 1.4873x; 1.4873x over previous
//
#include <hip/hip_runtime.h>
#include <hip/hip_bf16.h>
#include <stdint.h>

#define DMODEL 256
#define HEADS 8
#define EHEAD 32
#define BATCH 32
#define NB 4
#define LT 256
#define LC 128
#define SCALE_F 0.17677669529663687f  // 1/sqrt(32)

typedef __attribute__((ext_vector_type(8))) short short8;
typedef __attribute__((ext_vector_type(4))) float f32x4;
typedef __attribute__((ext_vector_type(4))) unsigned short us4;

#define ASG __attribute__((address_space(1)))
#define ASL __attribute__((address_space(3)))

__device__ __forceinline__ unsigned short bf16_rn(float f) {
    unsigned u = __float_as_uint(f);
    u += 0x7FFFu + ((u >> 16) & 1u);
    return (unsigned short)(u >> 16);
}
__device__ __forceinline__ float bf16_f(unsigned short h) {
    return __uint_as_float(((unsigned)h) << 16);
}

// ---------------------------------------------------------------------------
// Split fp32 -> bf16 hi + bf16 lo (residual). Vectorized x4.
// ---------------------------------------------------------------------------
__global__ void split_hi_lo(const float* __restrict__ src, unsigned short* __restrict__ hi,
                            unsigned short* __restrict__ lo, int n4)
{
    int i = blockIdx.x * blockDim.x + threadIdx.x;
    int stride = gridDim.x * blockDim.x;
    for (; i < n4; i += stride) {
        float4 a = ((const float4*)src)[i];
        float v[4] = {a.x, a.y, a.z, a.w};
        us4 h, l;
        #pragma unroll
        for (int j = 0; j < 4; ++j) {
            unsigned short hh = bf16_rn(v[j]);
            h[j] = hh;
            l[j] = bf16_rn(v[j] - bf16_f(hh));
        }
        ((us4*)hi)[i] = h;
        ((us4*)lo)[i] = l;
    }
}

// ---------------------------------------------------------------------------
// Transpose + split weights: W[z][k][n] fp32 -> Wt_hi/lo[z][n][k] bf16.
// Up to 4 weight sets in one launch; blockIdx.z = set*per_set + zi.
// ---------------------------------------------------------------------------
__global__ __launch_bounds__(256) void transpose_split(
    const float* __restrict__ W0, const float* __restrict__ W1,
    const float* __restrict__ W2, const float* __restrict__ W3,
    unsigned short* __restrict__ H0, unsigned short* __restrict__ L0,
    unsigned short* __restrict__ H1, unsigned short* __restrict__ L1,
    unsigned short* __restrict__ H2, unsigned short* __restrict__ L2,
    unsigned short* __restrict__ H3, unsigned short* __restrict__ L3,
    int per_set)
{
    const int z   = blockIdx.z;
    const int set = z / per_set;
    const int zi  = z - set * per_set;
    const float* W; unsigned short *H, *L;
    if      (set == 0) { W = W0; H = H0; L = L0; }
    else if (set == 1) { W = W1; H = H1; L = L1; }
    else if (set == 2) { W = W2; H = H2; L = L2; }
    else               { W = W3; H = H3; L = L3; }
    W += (long long)zi * 65536;
    H += (long long)zi * 65536;
    L += (long long)zi * 65536;

    __shared__ float tile[64][65];
    const int k0 = blockIdx.y * 64, n0 = blockIdx.x * 64;
    const int c = threadIdx.x & 63, r4 = threadIdx.x >> 6;

    #pragma unroll
    for (int i = 0; i < 16; ++i) {
        int kl = r4 + i * 4;
        tile[kl][c] = W[(long long)(k0 + kl) * 256 + n0 + c];
    }
    __syncthreads();
    #pragma unroll
    for (int i = 0; i < 16; ++i) {
        int nl = r4 + i * 4;
        float v = tile[c][nl];               // = W[k0+c][n0+nl]
        unsigned short hh = bf16_rn(v);
        unsigned short ll = bf16_rn(v - bf16_f(hh));
        long long o = (long long)(n0 + nl) * 256 + k0 + c;
        H[o] = hh;
        L[o] = ll;
    }
}

// ---------------------------------------------------------------------------
// bf16x3 MFMA GEMM: C[z] = (Ah+Al)[z] @ (Wh+Wl)[z] + bias[z]   (lo*lo dropped)
// A arrays: [M][256] bf16 row-major.  W arrays: [256 n][256 k] bf16 (pre-transposed).
// 128x128 tile, 256 threads (4 waves, 2x2), mfma_f32_16x16x32_bf16.
// Staging via global_load_lds(16B) with granule XOR swizzle kq ^= (row>>1)&3.
// M must be a multiple of 128.
// ---------------------------------------------------------------------------
__global__ __launch_bounds__(256, 2) void gemm_bf16x3(
    const unsigned short* __restrict__ Ah, const unsigned short* __restrict__ Al,
    const unsigned short* __restrict__ Bh, const unsigned short* __restrict__ Bl,
    const float* __restrict__ bias, float* __restrict__ C,
    long long sA, long long sW, long long sBias, long long sC)
{
    const int z = blockIdx.z;
    const char* aH = (const char*)(Ah + z * sA);
    const char* aL = (const char*)(Al + z * sA);
    const char* bH = (const char*)(Bh + z * sW);
    const char* bL = (const char*)(Bl + z * sW);
    const float* bz = bias + z * sBias;
    float* Cz = C + z * sC;

    const int bm = blockIdx.y * 128;
    const int bn = blockIdx.x * 128;
    const int tid = threadIdx.x;
    const int w = tid >> 6, l = tid & 63;
    const int wr = w >> 1, wc = w & 1;
    const int lr = l & 15, lk = l >> 4;

    __shared__ __align__(16) unsigned short lds[16384];   // 32 KiB
    unsigned short* lAh = lds;
    unsigned short* lAl = lds + 4096;
    unsigned short* lBh = lds + 8192;
    unsigned short* lBl = lds + 12288;

    // Staging: 512 16B-granules per array; thread handles granules g0, g1.
    // LDS granule g = (row, s); source k-granule kq = s ^ ((row>>1)&3).
    const int g0 = w * 64 + l;
    const int g1 = g0 + 256;
    const int row0 = g0 >> 2, kq0 = (g0 & 3) ^ ((row0 >> 1) & 3);
    const int row1 = g1 >> 2, kq1 = (g1 & 3) ^ ((row1 >> 1) & 3);
    const long long offA0 = (long long)(bm + row0) * 512 + kq0 * 16;
    const long long offA1 = (long long)(bm + row1) * 512 + kq1 * 16;
    const long long offB0 = (long long)(bn + row0) * 512 + kq0 * 16;
    const long long offB1 = (long long)(bn + row1) * 512 + kq1 * 16;

    f32x4 acc[4][4];
    #pragma unroll
    for (int m = 0; m < 4; ++m)
        #pragma unroll
        for (int n = 0; n < 4; ++n)
            acc[m][n] = (f32x4){0.f, 0.f, 0.f, 0.f};

    for (int k0 = 0; k0 < 256; k0 += 32) {
        const long long kb = (long long)k0 * 2;
        __builtin_amdgcn_global_load_lds((const ASG unsigned int*)(aH + offA0 + kb),
                                         (ASL unsigned int*)&lAh[g0 * 8], 16, 0, 0);
        __builtin_amdgcn_global_load_lds((const ASG unsigned int*)(aH + offA1 + kb),
                                         (ASL unsigned int*)&lAh[g1 * 8], 16, 0, 0);
        __builtin_amdgcn_global_load_lds((const ASG unsigned int*)(aL + offA0 + kb),
                                         (ASL unsigned int*)&lAl[g0 * 8], 16, 0, 0);
        __builtin_amdgcn_global_load_lds((const ASG unsigned int*)(aL + offA1 + kb),
                                         (ASL unsigned int*)&lAl[g1 * 8], 16, 0, 0);
        __builtin_amdgcn_global_load_lds((const ASG unsigned int*)(bH + offB0 + kb),
                                         (ASL unsigned int*)&lBh[g0 * 8], 16, 0, 0);
        __builtin_amdgcn_global_load_lds((const ASG unsigned int*)(bH + offB1 + kb),
                                         (ASL unsigned int*)&lBh[g1 * 8], 16, 0, 0);
        __builtin_amdgcn_global_load_lds((const ASG unsigned int*)(bL + offB0 + kb),
                                         (ASL unsigned int*)&lBl[g0 * 8], 16, 0, 0);
        __builtin_amdgcn_global_load_lds((const ASG unsigned int*)(bL + offB1 + kb),
                                         (ASL unsigned int*)&lBl[g1 * 8], 16, 0, 0);
        asm volatile("s_waitcnt vmcnt(0)" ::: "memory");
        __syncthreads();

        short8 fah[4], fal[4], fbh[4], fbl[4];
        #pragma unroll
        for (int m = 0; m < 4; ++m) {
            int row = wr * 64 + m * 16 + lr;
            int off = row * 32 + ((lk ^ ((row >> 1) & 3)) * 8);
            fah[m] = *(const short8*)&lAh[off];
            fal[m] = *(const short8*)&lAl[off];
        }
        #pragma unroll
        for (int n = 0; n < 4; ++n) {
            int row = wc * 64 + n * 16 + lr;
            int off = row * 32 + ((lk ^ ((row >> 1) & 3)) * 8);
            fbh[n] = *(const short8*)&lBh[off];
            fbl[n] = *(const short8*)&lBl[off];
        }
        #pragma unroll
        for (int m = 0; m < 4; ++m)
            #pragma unroll
            for (int n = 0; n < 4; ++n) {
                acc[m][n] = __builtin_amdgcn_mfma_f32_16x16x32_bf16(fah[m], fbh[n], acc[m][n], 0, 0, 0);
                acc[m][n] = __builtin_amdgcn_mfma_f32_16x16x32_bf16(fal[m], fbh[n], acc[m][n], 0, 0, 0);
                acc[m][n] = __builtin_amdgcn_mfma_f32_16x16x32_bf16(fah[m], fbl[n], acc[m][n], 0, 0, 0);
            }
        __syncthreads();
    }

    // Epilogue: C row = (lane>>4)*4 + reg, col = lane&15 (per fragment).
    #pragma unroll
    for (int n = 0; n < 4; ++n) {
        const int col = bn + wc * 64 + n * 16 + lr;
        const float bv = bz[col];
        #pragma unroll
        for (int m = 0; m < 4; ++m) {
            const int row = bm + wr * 64 + m * 16 + lk * 4;
            #pragma unroll
            for (int j = 0; j < 4; ++j)
                Cz[(long long)(row + j) * 256 + col] = acc[m][n][j] + bv;
        }
    }
}

// ---------------------------------------------------------------------------
// Intra-block multi-head attention (fp32, unchanged this round).
// ---------------------------------------------------------------------------
__global__ void attn_intra(const float* __restrict__ Q, const float* __restrict__ K,
                           const float* __restrict__ V, float* __restrict__ O, int L)
{
    extern __shared__ float ldsf[];
    float* Ks = ldsf;
    float* Vs = ldsf + (size_t)L * EHEAD;

    const int h = blockIdx.x;
    const long long base = (long long)blockIdx.y * L;
    const int tid = threadIdx.x;

    for (int idx = tid; idx < L * 8; idx += blockDim.x) {
        int s  = idx >> 3;
        int e4 = idx & 7;
        *(float4*)&Ks[s * EHEAD + e4 * 4] =
            *(const float4*)&K[(base + s) * DMODEL + h * EHEAD + e4 * 4];
        *(float4*)&Vs[s * EHEAD + e4 * 4] =
            *(const float4*)&V[(base + s) * DMODEL + h * EHEAD + e4 * 4];
    }
    __syncthreads();

    float4 q[8];
    #pragma unroll
    for (int i = 0; i < 8; ++i)
        q[i] = *(const float4*)&Q[(base + tid) * DMODEL + h * EHEAD + i * 4];

    float4 acc[8] = {};
    float m = -1e30f, lsum = 0.f;

    for (int s = 0; s < L; ++s) {
        float sc = 0.f;
        #pragma unroll
        for (int i = 0; i < 8; ++i) {
            float4 k4 = *(const float4*)&Ks[s * EHEAD + i * 4];
            sc = fmaf(q[i].x, k4.x, sc);
            sc = fmaf(q[i].y, k4.y, sc);
            sc = fmaf(q[i].z, k4.z, sc);
            sc = fmaf(q[i].w, k4.w, sc);
        }
        sc *= SCALE_F;
        float mn = fmaxf(m, sc);
        float r  = __expf(m - mn);
        float p  = __expf(sc - mn);
        lsum = lsum * r + p;
        #pragma unroll
        for (int i = 0; i < 8; ++i) {
            float4 v4 = *(const float4*)&Vs[s * EHEAD + i * 4];
            acc[i].x = fmaf(acc[i].x, r, p * v4.x);
            acc[i].y = fmaf(acc[i].y, r, p * v4.y);
            acc[i].z = fmaf(acc[i].z, r, p * v4.z);
            acc[i].w = fmaf(acc[i].w, r, p * v4.w);
        }
        m = mn;
    }

    const float inv = 1.f / lsum;
    #pragma unroll
    for (int i = 0; i < 8; ++i) {
        float4 o4;
        o4.x = acc[i].x * inv; o4.y = acc[i].y * inv;
        o4.z = acc[i].z * inv; o4.w = acc[i].w * inv;
        *(float4*)&O[(base + tid) * DMODEL + h * EHEAD + i * 4] = o4;
    }
}

__global__ void gather_routers(const float* __restrict__ xi, float* __restrict__ rt, int L)
{
    int t = blockIdx.x * blockDim.x + threadIdx.x;
    int d = t & 255;
    int r = t >> 8;
    int i = r & 3;
    int b = r >> 2;
    rt[(long long)r * DMODEL + d] =
        xi[(((long long)i * BATCH + b) * L + (L - 1)) * DMODEL + d];
}

__global__ void inter_attn(const float* __restrict__ RQ, const float* __restrict__ RK,
                           const float* __restrict__ RV, float* __restrict__ RA)
{
    int t = blockIdx.x * blockDim.x + threadIdx.x;
    int l = t & 3;
    int h = (t >> 2) & 7;
    int b = t >> 5;

    float q[EHEAD];
    #pragma unroll
    for (int e = 0; e < EHEAD; ++e)
        q[e] = RQ[((long long)b * 4 + l) * DMODEL + h * EHEAD + e];

    float sc[4];
    float m = -1e30f;
    #pragma unroll
    for (int s = 0; s < 4; ++s) {
        float d = 0.f;
        #pragma unroll
        for (int e = 0; e < EHEAD; ++e)
            d = fmaf(q[e], RK[((long long)b * 4 + s) * DMODEL + h * EHEAD + e], d);
        sc[s] = d * SCALE_F;
        m = fmaxf(m, sc[s]);
    }
    float lsum = 0.f;
    #pragma unroll
    for (int s = 0; s < 4; ++s) { sc[s] = __expf(sc[s] - m); lsum += sc[s]; }
    const float inv = 1.f / lsum;

    #pragma unroll
    for (int e = 0; e < EHEAD; ++e) {
        float a = 0.f;
        #pragma unroll
        for (int s = 0; s < 4; ++s)
            a = fmaf(sc[s], RV[((long long)b * 4 + s) * DMODEL + h * EHEAD + e], a);
        RA[((long long)b * 4 + l) * DMODEL + h * EHEAD + e] = a * inv;
    }
}

__global__ void scatter_routers(const float* __restrict__ ro, float* __restrict__ xi, int L)
{
    int t = blockIdx.x * blockDim.x + threadIdx.x;
    int d = t & 255;
    int r = t >> 8;
    int i = r & 3;
    int b = r >> 2;
    xi[(((long long)i * BATCH + b) * L + (L - 1)) * DMODEL + d] =
        ro[(long long)r * DMODEL + d];
}

// ---------------------------------------------------------------------------
struct BranchScratch {
    float *Qb, *Kb, *Vb, *AO;
    unsigned short *xh, *xl;          // reused for AO hi/lo after attention
    unsigned short *Wth[4], *Wtl[4];  // transposed weights
    unsigned short *WtIh[4], *WtIl[4];
    float *RT, *RQ, *RK, *RV, *RA, *RO;
    unsigned short *RTh, *RTl, *RAh, *RAl;
};

static void run_branch(const float* x,
    const float* Wq, const float* bq, const float* Wk, const float* bk,
    const float* Wv, const float* bv, const float* Wo, const float* bo,
    const float* Wqi, const float* bqi, const float* Wki, const float* bki,
    const float* Wvi, const float* bvi, const float* Woi, const float* boi,
    float* out, int L, const BranchScratch& S, hipStream_t stream)
{
    const int M = BATCH * L;                       // rows per nb-block
    const long long sX = (long long)M * DMODEL;
    const int nTot = NB * M * DMODEL;              // total activation elements

    split_hi_lo<<<1024, 256, 0, stream>>>(x, S.xh, S.xl, nTot / 4);
    transpose_split<<<dim3(4, 4, 16), 256, 0, stream>>>(
        Wq, Wk, Wv, Wo,
        S.Wth[0], S.Wtl[0], S.Wth[1], S.Wtl[1],
        S.Wth[2], S.Wtl[2], S.Wth[3], S.Wtl[3], 4);

    dim3 gProj(2, M / 128, NB);
    gemm_bf16x3<<<gProj, 256, 0, stream>>>(S.xh, S.xl, S.Wth[0], S.Wtl[0], bq, S.Qb, sX, 65536, 256, sX);
    gemm_bf16x3<<<gProj, 256, 0, stream>>>(S.xh, S.xl, S.Wth[1], S.Wtl[1], bk, S.Kb, sX, 65536, 256, sX);
    gemm_bf16x3<<<gProj, 256, 0, stream>>>(S.xh, S.xl, S.Wth[2], S.Wtl[2], bv, S.Vb, sX, 65536, 256, sX);

    dim3 gAtt(HEADS, NB * BATCH);
    size_t shmem = (size_t)L * EHEAD * 2 * sizeof(float);
    attn_intra<<<gAtt, L, shmem, stream>>>(S.Qb, S.Kb, S.Vb, S.AO, L);

    split_hi_lo<<<1024, 256, 0, stream>>>(S.AO, S.xh, S.xl, nTot / 4);
    gemm_bf16x3<<<gProj, 256, 0, stream>>>(S.xh, S.xl, S.Wth[3], S.Wtl[3], bo, out, sX, 65536, 256, sX);

    gather_routers<<<128, 256, 0, stream>>>(out, S.RT, L);
    split_hi_lo<<<32, 256, 0, stream>>>(S.RT, S.RTh, S.RTl, 128 * DMODEL / 4);
    transpose_split<<<dim3(4, 4, 4), 256, 0, stream>>>(
        Wqi, Wki, Wvi, Woi,
        S.WtIh[0], S.WtIl[0], S.WtIh[1], S.WtIl[1],
        S.WtIh[2], S.WtIl[2], S.WtIh[3], S.WtIl[3], 1);

    dim3 gI(2, 1, 1);
    gemm_bf16x3<<<gI, 256, 0, stream>>>(S.RTh, S.RTl, S.WtIh[0], S.WtIl[0], bqi, S.RQ, 0, 0, 0, 0);
    gemm_bf16x3<<<gI, 256, 0, stream>>>(S.RTh, S.RTl, S.WtIh[1], S.WtIl[1], bki, S.RK, 0, 0, 0, 0);
    gemm_bf16x3<<<gI, 256, 0, stream>>>(S.RTh, S.RTl, S.WtIh[2], S.WtIl[2], bvi, S.RV, 0, 0, 0, 0);

    inter_attn<<<4, 256, 0, stream>>>(S.RQ, S.RK, S.RV, S.RA);

    split_hi_lo<<<32, 256, 0, stream>>>(S.RA, S.RAh, S.RAl, 128 * DMODEL / 4);
    gemm_bf16x3<<<gI, 256, 0, stream>>>(S.RAh, S.RAl, S.WtIh[3], S.WtIl[3], boi, S.RO, 0, 0, 0, 0);

    scatter_routers<<<128, 256, 0, stream>>>(S.RO, out, L);
}

// ---------------------------------------------------------------------------
extern "C" void kernel_launch(void* const* d_in, const int* in_sizes, int n_in,
                              void* d_out, int out_size, void* d_ws, size_t ws_size,
                              hipStream_t stream)
{
    const float* x_t  = (const float*)d_in[0];
    const float* x_c  = (const float*)d_in[1];
    const float* Wq_t = (const float*)d_in[2];  const float* bq_t = (const float*)d_in[3];
    const float* Wk_t = (const float*)d_in[4];  const float* bk_t = (const float*)d_in[5];
    const float* Wv_t = (const float*)d_in[6];  const float* bv_t = (const float*)d_in[7];
    const float* Wo_t = (const float*)d_in[8];  const float* bo_t = (const float*)d_in[9];
    const float* Wq_c = (const float*)d_in[10]; const float* bq_c = (const float*)d_in[11];
    const float* Wk_c = (const float*)d_in[12]; const float* bk_c = (const float*)d_in[13];
    const float* Wv_c = (const float*)d_in[14]; const float* bv_c = (const float*)d_in[15];
    const float* Wo_c = (const float*)d_in[16]; const float* bo_c = (const float*)d_in[17];
    const float* Wq_it = (const float*)d_in[18]; const float* bq_it = (const float*)d_in[19];
    const float* Wk_it = (const float*)d_in[20]; const float* bk_it = (const float*)d_in[21];
    const float* Wv_it = (const float*)d_in[22]; const float* bv_it = (const float*)d_in[23];
    const float* Wo_it = (const float*)d_in[24]; const float* bo_it = (const float*)d_in[25];
    const float* Wq_ic = (const float*)d_in[26]; const float* bq_ic = (const float*)d_in[27];
    const float* Wk_ic = (const float*)d_in[28]; const float* bk_ic = (const float*)d_in[29];
    const float* Wv_ic = (const float*)d_in[30]; const float* bv_ic = (const float*)d_in[31];
    const float* Wo_ic = (const float*)d_in[32]; const float* bo_ic = (const float*)d_in[33];

    float* out = (float*)d_out;

    // ---- carve workspace ----
    char* p = (char*)d_ws;
    auto alloc = [&](size_t bytes) -> char* {
        char* r = p;
        p += (bytes + 255) & ~(size_t)255;
        return r;
    };
    const size_t QKV = (size_t)NB * BATCH * LT * DMODEL;   // 8,388,608 elements

    BranchScratch S;
    S.Qb = (float*)alloc(QKV * 4);
    S.Kb = (float*)alloc(QKV * 4);
    S.Vb = (float*)alloc(QKV * 4);
    S.AO = (float*)alloc(QKV * 4);
    S.xh = (unsigned short*)alloc(QKV * 2);
    S.xl = (unsigned short*)alloc(QKV * 2);
    for (int i = 0; i < 4; ++i) {
        S.Wth[i] = (unsigned short*)alloc((size_t)NB * 65536 * 2);
        S.Wtl[i] = (unsigned short*)alloc((size_t)NB * 65536 * 2);
    }
    for (int i = 0; i < 4; ++i) {
        S.WtIh[i] = (unsigned short*)alloc(65536 * 2);
        S.WtIl[i] = (unsigned short*)alloc(65536 * 2);
    }
    S.RT = (float*)alloc(128 * DMODEL * 4);
    S.RQ = (float*)alloc(128 * DMODEL * 4);
    S.RK = (float*)alloc(128 * DMODEL * 4);
    S.RV = (float*)alloc(128 * DMODEL * 4);
    S.RA = (float*)alloc(128 * DMODEL * 4);
    S.RO = (float*)alloc(128 * DMODEL * 4);
    S.RTh = (unsigned short*)alloc(128 * DMODEL * 2);
    S.RTl = (unsigned short*)alloc(128 * DMODEL * 2);
    S.RAh = (unsigned short*)alloc(128 * DMODEL * 2);
    S.RAl = (unsigned short*)alloc(128 * DMODEL * 2);

    run_branch(x_t, Wq_t, bq_t, Wk_t, bk_t, Wv_t, bv_t, Wo_t, bo_t,
               Wq_it, bq_it, Wk_it, bk_it, Wv_it, bv_it, Wo_it, bo_it,
               out, LT, S, stream);

    float* out_c = out + (size_t)NB * BATCH * LT * DMODEL;
    run_branch(x_c, Wq_c, bq_c, Wk_c, bk_c, Wv_c, bv_c, Wo_c, bo_c,
               Wq_ic, bq_ic, Wk_ic, bk_ic, Wv_ic, bv_ic, Wo_ic, bo_ic,
               out_c, LC, S, stream);
}

// Round 3
// 516.001 us; speedup vs baseline: 2.0258x; 1.3620x over previous
//
#include <hip/hip_runtime.h>
#include <hip/hip_bf16.h>
#include <stdint.h>

#define DMODEL 256
#define HEADS 8
#define EHEAD 32
#define BATCH 32
#define NB 4
#define LT 256
#define LC 128
#define SCALE_F 0.17677669529663687f  // 1/sqrt(32)

typedef __attribute__((ext_vector_type(8))) short short8;
typedef __attribute__((ext_vector_type(4))) float f32x4;
typedef __attribute__((ext_vector_type(4))) unsigned short us4;

#define ASG __attribute__((address_space(1)))
#define ASL __attribute__((address_space(3)))

__device__ __forceinline__ unsigned short bf16_rn(float f) {
    unsigned u = __float_as_uint(f);
    u += 0x7FFFu + ((u >> 16) & 1u);
    return (unsigned short)(u >> 16);
}
__device__ __forceinline__ float bf16_f(unsigned short h) {
    return __uint_as_float(((unsigned)h) << 16);
}

// ---------------------------------------------------------------------------
// Split fp32 -> bf16 hi + bf16 lo (residual). Vectorized x4.
// ---------------------------------------------------------------------------
__global__ void split_hi_lo(const float* __restrict__ src, unsigned short* __restrict__ hi,
                            unsigned short* __restrict__ lo, int n4)
{
    int i = blockIdx.x * blockDim.x + threadIdx.x;
    int stride = gridDim.x * blockDim.x;
    for (; i < n4; i += stride) {
        float4 a = ((const float4*)src)[i];
        float v[4] = {a.x, a.y, a.z, a.w};
        us4 h, l;
        #pragma unroll
        for (int j = 0; j < 4; ++j) {
            unsigned short hh = bf16_rn(v[j]);
            h[j] = hh;
            l[j] = bf16_rn(v[j] - bf16_f(hh));
        }
        ((us4*)hi)[i] = h;
        ((us4*)lo)[i] = l;
    }
}

// ---------------------------------------------------------------------------
// Transpose + split weights: W[z][k][n] fp32 -> Wt_hi/lo[z][n][k] bf16.
// ---------------------------------------------------------------------------
__global__ __launch_bounds__(256) void transpose_split(
    const float* __restrict__ W0, const float* __restrict__ W1,
    const float* __restrict__ W2, const float* __restrict__ W3,
    unsigned short* __restrict__ H0, unsigned short* __restrict__ L0,
    unsigned short* __restrict__ H1, unsigned short* __restrict__ L1,
    unsigned short* __restrict__ H2, unsigned short* __restrict__ L2,
    unsigned short* __restrict__ H3, unsigned short* __restrict__ L3,
    int per_set)
{
    const int z   = blockIdx.z;
    const int set = z / per_set;
    const int zi  = z - set * per_set;
    const float* W; unsigned short *H, *L;
    if      (set == 0) { W = W0; H = H0; L = L0; }
    else if (set == 1) { W = W1; H = H1; L = L1; }
    else if (set == 2) { W = W2; H = H2; L = L2; }
    else               { W = W3; H = H3; L = L3; }
    W += (long long)zi * 65536;
    H += (long long)zi * 65536;
    L += (long long)zi * 65536;

    __shared__ float tile[64][65];
    const int k0 = blockIdx.y * 64, n0 = blockIdx.x * 64;
    const int c = threadIdx.x & 63, r4 = threadIdx.x >> 6;

    #pragma unroll
    for (int i = 0; i < 16; ++i) {
        int kl = r4 + i * 4;
        tile[kl][c] = W[(long long)(k0 + kl) * 256 + n0 + c];
    }
    __syncthreads();
    #pragma unroll
    for (int i = 0; i < 16; ++i) {
        int nl = r4 + i * 4;
        float v = tile[c][nl];
        unsigned short hh = bf16_rn(v);
        unsigned short ll = bf16_rn(v - bf16_f(hh));
        long long o = (long long)(n0 + nl) * 256 + k0 + c;
        H[o] = hh;
        L[o] = ll;
    }
}

// ---------------------------------------------------------------------------
// Shared GEMM body: bf16x3, 128x128 tile, 4 waves, mfma_f32_16x16x32_bf16.
// OUT_MODE 0: fp32 C = acc+bias.  OUT_MODE 1: bf16 C = rn((acc+bias)*scale).
// ---------------------------------------------------------------------------
template<int OUT_MODE>
__global__ __launch_bounds__(256, 2) void gemm_bf16x3_t(
    const unsigned short* __restrict__ Ah, const unsigned short* __restrict__ Al,
    const unsigned short* __restrict__ Bh, const unsigned short* __restrict__ Bl,
    const float* __restrict__ bias, void* __restrict__ Cv, float scale,
    long long sA, long long sW, long long sBias, long long sC)
{
    const int z = blockIdx.z;
    const char* aH = (const char*)(Ah + z * sA);
    const char* aL = (const char*)(Al + z * sA);
    const char* bH = (const char*)(Bh + z * sW);
    const char* bL = (const char*)(Bl + z * sW);
    const float* bz = bias + z * sBias;

    const int bm = blockIdx.y * 128;
    const int bn = blockIdx.x * 128;
    const int tid = threadIdx.x;
    const int w = tid >> 6, l = tid & 63;
    const int wr = w >> 1, wc = w & 1;
    const int lr = l & 15, lk = l >> 4;

    __shared__ __align__(16) unsigned short lds[16384];   // 32 KiB
    unsigned short* lAh = lds;
    unsigned short* lAl = lds + 4096;
    unsigned short* lBh = lds + 8192;
    unsigned short* lBl = lds + 12288;

    const int g0 = w * 64 + l;
    const int g1 = g0 + 256;
    const int row0 = g0 >> 2, kq0 = (g0 & 3) ^ ((row0 >> 1) & 3);
    const int row1 = g1 >> 2, kq1 = (g1 & 3) ^ ((row1 >> 1) & 3);
    const long long offA0 = (long long)(bm + row0) * 512 + kq0 * 16;
    const long long offA1 = (long long)(bm + row1) * 512 + kq1 * 16;
    const long long offB0 = (long long)(bn + row0) * 512 + kq0 * 16;
    const long long offB1 = (long long)(bn + row1) * 512 + kq1 * 16;

    f32x4 acc[4][4];
    #pragma unroll
    for (int m = 0; m < 4; ++m)
        #pragma unroll
        for (int n = 0; n < 4; ++n)
            acc[m][n] = (f32x4){0.f, 0.f, 0.f, 0.f};

    for (int k0 = 0; k0 < 256; k0 += 32) {
        const long long kb = (long long)k0 * 2;
        __builtin_amdgcn_global_load_lds((const ASG unsigned int*)(aH + offA0 + kb),
                                         (ASL unsigned int*)&lAh[g0 * 8], 16, 0, 0);
        __builtin_amdgcn_global_load_lds((const ASG unsigned int*)(aH + offA1 + kb),
                                         (ASL unsigned int*)&lAh[g1 * 8], 16, 0, 0);
        __builtin_amdgcn_global_load_lds((const ASG unsigned int*)(aL + offA0 + kb),
                                         (ASL unsigned int*)&lAl[g0 * 8], 16, 0, 0);
        __builtin_amdgcn_global_load_lds((const ASG unsigned int*)(aL + offA1 + kb),
                                         (ASL unsigned int*)&lAl[g1 * 8], 16, 0, 0);
        __builtin_amdgcn_global_load_lds((const ASG unsigned int*)(bH + offB0 + kb),
                                         (ASL unsigned int*)&lBh[g0 * 8], 16, 0, 0);
        __builtin_amdgcn_global_load_lds((const ASG unsigned int*)(bH + offB1 + kb),
                                         (ASL unsigned int*)&lBh[g1 * 8], 16, 0, 0);
        __builtin_amdgcn_global_load_lds((const ASG unsigned int*)(bL + offB0 + kb),
                                         (ASL unsigned int*)&lBl[g0 * 8], 16, 0, 0);
        __builtin_amdgcn_global_load_lds((const ASG unsigned int*)(bL + offB1 + kb),
                                         (ASL unsigned int*)&lBl[g1 * 8], 16, 0, 0);
        asm volatile("s_waitcnt vmcnt(0)" ::: "memory");
        __syncthreads();

        short8 fah[4], fal[4], fbh[4], fbl[4];
        #pragma unroll
        for (int m = 0; m < 4; ++m) {
            int row = wr * 64 + m * 16 + lr;
            int off = row * 32 + ((lk ^ ((row >> 1) & 3)) * 8);
            fah[m] = *(const short8*)&lAh[off];
            fal[m] = *(const short8*)&lAl[off];
        }
        #pragma unroll
        for (int n = 0; n < 4; ++n) {
            int row = wc * 64 + n * 16 + lr;
            int off = row * 32 + ((lk ^ ((row >> 1) & 3)) * 8);
            fbh[n] = *(const short8*)&lBh[off];
            fbl[n] = *(const short8*)&lBl[off];
        }
        #pragma unroll
        for (int m = 0; m < 4; ++m)
            #pragma unroll
            for (int n = 0; n < 4; ++n) {
                acc[m][n] = __builtin_amdgcn_mfma_f32_16x16x32_bf16(fah[m], fbh[n], acc[m][n], 0, 0, 0);
                acc[m][n] = __builtin_amdgcn_mfma_f32_16x16x32_bf16(fal[m], fbh[n], acc[m][n], 0, 0, 0);
                acc[m][n] = __builtin_amdgcn_mfma_f32_16x16x32_bf16(fah[m], fbl[n], acc[m][n], 0, 0, 0);
            }
        __syncthreads();
    }

    #pragma unroll
    for (int n = 0; n < 4; ++n) {
        const int col = bn + wc * 64 + n * 16 + lr;
        const float bv = bz[col];
        #pragma unroll
        for (int m = 0; m < 4; ++m) {
            const int row = bm + wr * 64 + m * 16 + lk * 4;
            #pragma unroll
            for (int j = 0; j < 4; ++j) {
                float v = acc[m][n][j] + bv;
                if (OUT_MODE == 0) {
                    ((float*)Cv)[z * sC + (long long)(row + j) * 256 + col] = v;
                } else {
                    ((unsigned short*)Cv)[z * sC + (long long)(row + j) * 256 + col] =
                        bf16_rn(v * scale);
                }
            }
        }
    }
}

// ---------------------------------------------------------------------------
// V transpose per (blkb, head): Vbf [blkb*L + kv][256] -> VT [blkb][h][e][L]
// ---------------------------------------------------------------------------
template<int L>
__global__ __launch_bounds__(256) void v_transpose(
    const unsigned short* __restrict__ Vbf, unsigned short* __restrict__ VT)
{
    __shared__ unsigned short tile[L * 36];    // rows kv, 32 cols + pad 4
    const int h = blockIdx.x, blkb = blockIdx.y, tid = threadIdx.x;
    const unsigned short* src = Vbf + (long long)blkb * L * 256 + h * 32;
    unsigned short* dst = VT + ((long long)blkb * HEADS + h) * 32 * L;

    #pragma unroll
    for (int i = 0; i < L * 8 / 256; ++i) {
        int ci = i * 256 + tid;
        int kv = ci >> 3, e0 = (ci & 7) * 4;
        us4 v = *(const us4*)(src + (long long)kv * 256 + e0);
        *(us4*)(&tile[kv * 36 + e0]) = v;
    }
    __syncthreads();
    #pragma unroll
    for (int i = 0; i < L * 8 / 256; ++i) {
        int ci = i * 256 + tid;
        int e = ci / (L / 4), kvc = ci % (L / 4);
        us4 v;
        #pragma unroll
        for (int j = 0; j < 4; ++j) v[j] = tile[(kvc * 4 + j) * 36 + e];
        *(us4*)(dst + (long long)e * L + kvc * 4) = v;
    }
}

// ---------------------------------------------------------------------------
// MFMA flash attention per (head, blkb).  Q pre-scaled by SCALE*log2e.
// 4 waves; wave w owns q rows [w*L/4, (w+1)*L/4).  Swapped QK^T (S^T), P via
// per-wave swizzled LDS, PV from staged V^T.  Emits AO as bf16 hi+lo.
// ---------------------------------------------------------------------------
template<int L>
__global__ __launch_bounds__(256) void attn_mfma(
    const unsigned short* __restrict__ Qbf, const unsigned short* __restrict__ Kbf,
    const unsigned short* __restrict__ VT,
    unsigned short* __restrict__ AOh, unsigned short* __restrict__ AOl)
{
    constexpr int KV_FRAGS    = L / 16;
    constexpr int PV_STEPS    = L / 32;
    constexpr int QT_PER_WAVE = L / 64;
    constexpr int K_BYTES     = L * 64;
    constexpr int GPR         = L / 8;      // 16B granules per VT row

    __shared__ __align__(16) char smem[L * 256];
    unsigned short* Ks  = (unsigned short*)smem;                       // [L][32] swz
    unsigned short* VTs = (unsigned short*)(smem + K_BYTES);           // [32][L] swz
    unsigned short* Pa  = (unsigned short*)(smem + 2 * K_BYTES);       // 4x[16][L] swz

    const int h    = blockIdx.x;
    const int blkb = blockIdx.y;
    const int tid  = threadIdx.x;
    const int w    = tid >> 6;
    const int l    = tid & 63;
    const int lq   = l & 15;
    const int lg   = l >> 4;

    const long long rowbase = (long long)blkb * L;
    const unsigned short* Kh = Kbf + rowbase * 256 + h * 32;
    const unsigned short* Qh = Qbf + rowbase * 256 + h * 32;
    const unsigned short* Vh = VT + ((long long)blkb * HEADS + h) * (32 * L);

    // stage K: physical granule gi holds logical granule (gi&3)^((row>>1)&3)
    #pragma unroll
    for (int i = 0; i < K_BYTES / 16 / 256; ++i) {
        int gi = i * 256 + tid;
        int row = gi >> 2;
        int gsrc = (gi & 3) ^ ((row >> 1) & 3);
        __builtin_amdgcn_global_load_lds(
            (const ASG unsigned int*)(Kh + (long long)row * 256 + gsrc * 8),
            (ASL unsigned int*)(Ks + gi * 8), 16, 0, 0);
    }
    // stage VT: physical granule gp in row e holds logical gp^(e&7)
    #pragma unroll
    for (int i = 0; i < K_BYTES / 16 / 256; ++i) {
        int gi = i * 256 + tid;
        int e  = gi / GPR;
        int gsrc = (gi % GPR) ^ (e & 7);
        __builtin_amdgcn_global_load_lds(
            (const ASG unsigned int*)(Vh + (long long)e * L + gsrc * 8),
            (ASL unsigned int*)(VTs + gi * 8), 16, 0, 0);
    }
    asm volatile("s_waitcnt vmcnt(0)" ::: "memory");
    __syncthreads();

    unsigned short* Pw = Pa + w * (16 * L);

    for (int qt = 0; qt < QT_PER_WAVE; ++qt) {
        const int q0 = w * (QT_PER_WAVE * 16) + qt * 16;
        short8 qf = *(const short8*)(Qh + (long long)(q0 + lq) * 256 + lg * 8);

        // S^T = K · Q^T  (lane: col q = lq, rows kv = 16t + 4*lg + j)
        f32x4 sf[KV_FRAGS];
        #pragma unroll
        for (int t = 0; t < KV_FRAGS; ++t) {
            int row = t * 16 + lq;
            int off = row * 32 + ((lg ^ ((row >> 1) & 3)) * 8);
            short8 kf = *(const short8*)(Ks + off);
            sf[t] = __builtin_amdgcn_mfma_f32_16x16x32_bf16(kf, qf,
                        (f32x4){0.f, 0.f, 0.f, 0.f}, 0, 0, 0);
        }
        // softmax, no max-sub (scores tiny; clamp for safety)
        float lsum = 0.f;
        unsigned short pb[KV_FRAGS][4];
        #pragma unroll
        for (int t = 0; t < KV_FRAGS; ++t)
            #pragma unroll
            for (int j = 0; j < 4; ++j) {
                float s = fminf(fmaxf(sf[t][j], -60.f), 60.f);
                float p = __builtin_exp2f(s);
                lsum += p;
                pb[t][j] = bf16_rn(p);
            }
        lsum += __shfl_xor(lsum, 16);
        lsum += __shfl_xor(lsum, 32);

        // write P (A layout [q][kv], 8B slots XOR (q&14))
        #pragma unroll
        for (int t = 0; t < KV_FRAGS; ++t) {
            us4 v; v[0] = pb[t][0]; v[1] = pb[t][1]; v[2] = pb[t][2]; v[3] = pb[t][3];
            int slot = (t * 4 + lg) ^ (lq & 14);
            *(us4*)(Pw + lq * L + slot * 4) = v;
        }
        asm volatile("s_waitcnt lgkmcnt(0)" ::: "memory");

        // PV: O[q][e] = sum_kv P[q][kv] * VT[e][kv]
        f32x4 oacc[2] = {(f32x4){0.f,0.f,0.f,0.f}, (f32x4){0.f,0.f,0.f,0.f}};
        #pragma unroll
        for (int s = 0; s < PV_STEPS; ++s) {
            int pslot = (s * 8 + lg * 2) ^ (lq & 14);
            short8 pf = *(const short8*)(Pw + lq * L + pslot * 4);
            #pragma unroll
            for (int et = 0; et < 2; ++et) {
                int e = et * 16 + lq;
                int gk = (s * 4 + lg) ^ (e & 7);
                short8 vf = *(const short8*)(VTs + e * L + gk * 8);
                oacc[et] = __builtin_amdgcn_mfma_f32_16x16x32_bf16(pf, vf, oacc[et], 0, 0, 0);
            }
        }
        // epilogue: rows q = q0 + 4*lg + j, col e = et*16 + lq
        float inv[4];
        #pragma unroll
        for (int j = 0; j < 4; ++j)
            inv[j] = 1.f / __shfl(lsum, lg * 4 + j);
        #pragma unroll
        for (int et = 0; et < 2; ++et)
            #pragma unroll
            for (int j = 0; j < 4; ++j) {
                long long row = rowbase + q0 + lg * 4 + j;
                int col = h * 32 + et * 16 + lq;
                float o = oacc[et][j] * inv[j];
                unsigned short hi = bf16_rn(o);
                unsigned short lo = bf16_rn(o - bf16_f(hi));
                AOh[row * 256 + col] = hi;
                AOl[row * 256 + col] = lo;
            }
    }
}

// ---------------------------------------------------------------------------
__global__ void gather_routers(const float* __restrict__ xi, float* __restrict__ rt, int L)
{
    int t = blockIdx.x * blockDim.x + threadIdx.x;
    int d = t & 255;
    int r = t >> 8;
    int i = r & 3;
    int b = r >> 2;
    rt[(long long)r * DMODEL + d] =
        xi[(((long long)i * BATCH + b) * L + (L - 1)) * DMODEL + d];
}

__global__ void inter_attn(const float* __restrict__ RQ, const float* __restrict__ RK,
                           const float* __restrict__ RV, float* __restrict__ RA)
{
    int t = blockIdx.x * blockDim.x + threadIdx.x;
    int l = t & 3;
    int h = (t >> 2) & 7;
    int b = t >> 5;

    float q[EHEAD];
    #pragma unroll
    for (int e = 0; e < EHEAD; ++e)
        q[e] = RQ[((long long)b * 4 + l) * DMODEL + h * EHEAD + e];

    float sc[4];
    float m = -1e30f;
    #pragma unroll
    for (int s = 0; s < 4; ++s) {
        float d = 0.f;
        #pragma unroll
        for (int e = 0; e < EHEAD; ++e)
            d = fmaf(q[e], RK[((long long)b * 4 + s) * DMODEL + h * EHEAD + e], d);
        sc[s] = d * SCALE_F;
        m = fmaxf(m, sc[s]);
    }
    float lsum = 0.f;
    #pragma unroll
    for (int s = 0; s < 4; ++s) { sc[s] = __expf(sc[s] - m); lsum += sc[s]; }
    const float inv = 1.f / lsum;

    #pragma unroll
    for (int e = 0; e < EHEAD; ++e) {
        float a = 0.f;
        #pragma unroll
        for (int s = 0; s < 4; ++s)
            a = fmaf(sc[s], RV[((long long)b * 4 + s) * DMODEL + h * EHEAD + e], a);
        RA[((long long)b * 4 + l) * DMODEL + h * EHEAD + e] = a * inv;
    }
}

__global__ void scatter_routers(const float* __restrict__ ro, float* __restrict__ xi, int L)
{
    int t = blockIdx.x * blockDim.x + threadIdx.x;
    int d = t & 255;
    int r = t >> 8;
    int i = r & 3;
    int b = r >> 2;
    xi[(((long long)i * BATCH + b) * L + (L - 1)) * DMODEL + d] =
        ro[(long long)r * DMODEL + d];
}

// ---------------------------------------------------------------------------
struct BranchScratch {
    unsigned short *xh, *xl;
    unsigned short *Qbf, *Kbf, *Vbf, *VTb, *AOh, *AOl;
    unsigned short *Wth[4], *Wtl[4];
    unsigned short *WtIh[4], *WtIl[4];
    float *RT, *RQ, *RK, *RV, *RA, *RO;
    unsigned short *RTh, *RTl, *RAh, *RAl;
};

template<int L>
static void run_branch(const float* x,
    const float* Wq, const float* bq, const float* Wk, const float* bk,
    const float* Wv, const float* bv, const float* Wo, const float* bo,
    const float* Wqi, const float* bqi, const float* Wki, const float* bki,
    const float* Wvi, const float* bvi, const float* Woi, const float* boi,
    float* out, const BranchScratch& S, hipStream_t stream)
{
    const int M = BATCH * L;
    const long long sX = (long long)M * DMODEL;
    const int nTot = NB * M * DMODEL;
    const float CS = 0.17677669529663687f * 1.4426950408889634f;  // SCALE*log2(e)

    split_hi_lo<<<1024, 256, 0, stream>>>(x, S.xh, S.xl, nTot / 4);
    transpose_split<<<dim3(4, 4, 16), 256, 0, stream>>>(
        Wq, Wk, Wv, Wo,
        S.Wth[0], S.Wtl[0], S.Wth[1], S.Wtl[1],
        S.Wth[2], S.Wtl[2], S.Wth[3], S.Wtl[3], 4);

    dim3 gProj(2, M / 128, NB);
    gemm_bf16x3_t<1><<<gProj, 256, 0, stream>>>(S.xh, S.xl, S.Wth[0], S.Wtl[0], bq, S.Qbf, CS,   sX, 65536, 256, sX);
    gemm_bf16x3_t<1><<<gProj, 256, 0, stream>>>(S.xh, S.xl, S.Wth[1], S.Wtl[1], bk, S.Kbf, 1.0f, sX, 65536, 256, sX);
    gemm_bf16x3_t<1><<<gProj, 256, 0, stream>>>(S.xh, S.xl, S.Wth[2], S.Wtl[2], bv, S.Vbf, 1.0f, sX, 65536, 256, sX);

    v_transpose<L><<<dim3(HEADS, NB * BATCH), 256, 0, stream>>>(S.Vbf, S.VTb);
    attn_mfma<L><<<dim3(HEADS, NB * BATCH), 256, 0, stream>>>(S.Qbf, S.Kbf, S.VTb, S.AOh, S.AOl);

    gemm_bf16x3_t<0><<<gProj, 256, 0, stream>>>(S.AOh, S.AOl, S.Wth[3], S.Wtl[3], bo, out, 1.0f, sX, 65536, 256, sX);

    gather_routers<<<128, 256, 0, stream>>>(out, S.RT, L);
    split_hi_lo<<<32, 256, 0, stream>>>(S.RT, S.RTh, S.RTl, 128 * DMODEL / 4);
    transpose_split<<<dim3(4, 4, 4), 256, 0, stream>>>(
        Wqi, Wki, Wvi, Woi,
        S.WtIh[0], S.WtIl[0], S.WtIh[1], S.WtIl[1],
        S.WtIh[2], S.WtIl[2], S.WtIh[3], S.WtIl[3], 1);

    dim3 gI(2, 1, 1);
    gemm_bf16x3_t<0><<<gI, 256, 0, stream>>>(S.RTh, S.RTl, S.WtIh[0], S.WtIl[0], bqi, S.RQ, 1.0f, 0, 0, 0, 0);
    gemm_bf16x3_t<0><<<gI, 256, 0, stream>>>(S.RTh, S.RTl, S.WtIh[1], S.WtIl[1], bki, S.RK, 1.0f, 0, 0, 0, 0);
    gemm_bf16x3_t<0><<<gI, 256, 0, stream>>>(S.RTh, S.RTl, S.WtIh[2], S.WtIl[2], bvi, S.RV, 1.0f, 0, 0, 0, 0);

    inter_attn<<<4, 256, 0, stream>>>(S.RQ, S.RK, S.RV, S.RA);

    split_hi_lo<<<32, 256, 0, stream>>>(S.RA, S.RAh, S.RAl, 128 * DMODEL / 4);
    gemm_bf16x3_t<0><<<gI, 256, 0, stream>>>(S.RAh, S.RAl, S.WtIh[3], S.WtIl[3], boi, S.RO, 1.0f, 0, 0, 0, 0);

    scatter_routers<<<128, 256, 0, stream>>>(S.RO, out, L);
}

// ---------------------------------------------------------------------------
extern "C" void kernel_launch(void* const* d_in, const int* in_sizes, int n_in,
                              void* d_out, int out_size, void* d_ws, size_t ws_size,
                              hipStream_t stream)
{
    const float* x_t  = (const float*)d_in[0];
    const float* x_c  = (const float*)d_in[1];
    const float* Wq_t = (const float*)d_in[2];  const float* bq_t = (const float*)d_in[3];
    const float* Wk_t = (const float*)d_in[4];  const float* bk_t = (const float*)d_in[5];
    const float* Wv_t = (const float*)d_in[6];  const float* bv_t = (const float*)d_in[7];
    const float* Wo_t = (const float*)d_in[8];  const float* bo_t = (const float*)d_in[9];
    const float* Wq_c = (const float*)d_in[10]; const float* bq_c = (const float*)d_in[11];
    const float* Wk_c = (const float*)d_in[12]; const float* bk_c = (const float*)d_in[13];
    const float* Wv_c = (const float*)d_in[14]; const float* bv_c = (const float*)d_in[15];
    const float* Wo_c = (const float*)d_in[16]; const float* bo_c = (const float*)d_in[17];
    const float* Wq_it = (const float*)d_in[18]; const float* bq_it = (const float*)d_in[19];
    const float* Wk_it = (const float*)d_in[20]; const float* bk_it = (const float*)d_in[21];
    const float* Wv_it = (const float*)d_in[22]; const float* bv_it = (const float*)d_in[23];
    const float* Wo_it = (const float*)d_in[24]; const float* bo_it = (const float*)d_in[25];
    const float* Wq_ic = (const float*)d_in[26]; const float* bq_ic = (const float*)d_in[27];
    const float* Wk_ic = (const float*)d_in[28]; const float* bk_ic = (const float*)d_in[29];
    const float* Wv_ic = (const float*)d_in[30]; const float* bv_ic = (const float*)d_in[31];
    const float* Wo_ic = (const float*)d_in[32]; const float* bo_ic = (const float*)d_in[33];

    float* out = (float*)d_out;

    char* p = (char*)d_ws;
    auto alloc = [&](size_t bytes) -> char* {
        char* r = p;
        p += (bytes + 255) & ~(size_t)255;
        return r;
    };
    const size_t QKV = (size_t)NB * BATCH * LT * DMODEL;   // 8,388,608 elements

    BranchScratch S;
    S.xh  = (unsigned short*)alloc(QKV * 2);
    S.xl  = (unsigned short*)alloc(QKV * 2);
    S.Qbf = (unsigned short*)alloc(QKV * 2);
    S.Kbf = (unsigned short*)alloc(QKV * 2);
    S.Vbf = (unsigned short*)alloc(QKV * 2);
    S.VTb = (unsigned short*)alloc(QKV * 2);
    S.AOh = (unsigned short*)alloc(QKV * 2);
    S.AOl = (unsigned short*)alloc(QKV * 2);
    for (int i = 0; i < 4; ++i) {
        S.Wth[i] = (unsigned short*)alloc((size_t)NB * 65536 * 2);
        S.Wtl[i] = (unsigned short*)alloc((size_t)NB * 65536 * 2);
    }
    for (int i = 0; i < 4; ++i) {
        S.WtIh[i] = (unsigned short*)alloc(65536 * 2);
        S.WtIl[i] = (unsigned short*)alloc(65536 * 2);
    }
    S.RT = (float*)alloc(128 * DMODEL * 4);
    S.RQ = (float*)alloc(128 * DMODEL * 4);
    S.RK = (float*)alloc(128 * DMODEL * 4);
    S.RV = (float*)alloc(128 * DMODEL * 4);
    S.RA = (float*)alloc(128 * DMODEL * 4);
    S.RO = (float*)alloc(128 * DMODEL * 4);
    S.RTh = (unsigned short*)alloc(128 * DMODEL * 2);
    S.RTl = (unsigned short*)alloc(128 * DMODEL * 2);
    S.RAh = (unsigned short*)alloc(128 * DMODEL * 2);
    S.RAl = (unsigned short*)alloc(128 * DMODEL * 2);

    run_branch<LT>(x_t, Wq_t, bq_t, Wk_t, bk_t, Wv_t, bv_t, Wo_t, bo_t,
                   Wq_it, bq_it, Wk_it, bk_it, Wv_it, bv_it, Wo_it, bo_it,
                   out, S, stream);

    float* out_c = out + (size_t)NB * BATCH * LT * DMODEL;
    run_branch<LC>(x_c, Wq_c, bq_c, Wk_c, bk_c, Wv_c, bv_c, Wo_c, bo_c,
                   Wq_ic, bq_ic, Wk_ic, bk_ic, Wv_ic, bv_ic, Wo_ic, bo_ic,
                   out_c, S, stream);
}

// Round 4
// 431.108 us; speedup vs baseline: 2.4247x; 1.1969x over previous
//
#include <hip/hip_runtime.h>
#include <hip/hip_bf16.h>
#include <stdint.h>

#define DMODEL 256
#define HEADS 8
#define EHEAD 32
#define BATCH 32
#define NB 4
#define LT 256
#define LC 128

typedef __attribute__((ext_vector_type(8))) short short8;
typedef __attribute__((ext_vector_type(4))) float f32x4;
typedef __attribute__((ext_vector_type(4))) unsigned short us4;

#define ASG __attribute__((address_space(1)))
#define ASL __attribute__((address_space(3)))

__device__ __forceinline__ unsigned short bf16_rn(float f) {
    unsigned u = __float_as_uint(f);
    u += 0x7FFFu + ((u >> 16) & 1u);
    return (unsigned short)(u >> 16);
}
__device__ __forceinline__ float bf16_f(unsigned short h) {
    return __uint_as_float(((unsigned)h) << 16);
}

// ---------------------------------------------------------------------------
// Split fp32 -> bf16 hi + bf16 lo (residual). Vectorized x4.
// ---------------------------------------------------------------------------
__global__ void split_hi_lo(const float* __restrict__ src, unsigned short* __restrict__ hi,
                            unsigned short* __restrict__ lo, int n4)
{
    int i = blockIdx.x * blockDim.x + threadIdx.x;
    int stride = gridDim.x * blockDim.x;
    for (; i < n4; i += stride) {
        float4 a = ((const float4*)src)[i];
        float v[4] = {a.x, a.y, a.z, a.w};
        us4 h, l;
        #pragma unroll
        for (int j = 0; j < 4; ++j) {
            unsigned short hh = bf16_rn(v[j]);
            h[j] = hh;
            l[j] = bf16_rn(v[j] - bf16_f(hh));
        }
        ((us4*)hi)[i] = h;
        ((us4*)lo)[i] = l;
    }
}

// ---------------------------------------------------------------------------
// All-weight transpose+split in ONE launch. Sets 0-3: per-block main weights
// (zi = 0..3); sets 4-7: inter weights (zi = 0). grid (4,4,20).
// W[z][k][n] fp32 -> H/L[z][n][k] bf16 hi/lo.
// ---------------------------------------------------------------------------
struct PrepArgs {
    const float* W[8];
    unsigned short* H[8];
    unsigned short* Lo[8];
};

__global__ __launch_bounds__(256) void prep_weights(PrepArgs pa)
{
    const int z = blockIdx.z;
    int set, zi;
    if (z < 16) { set = z >> 2; zi = z & 3; } else { set = 4 + (z - 16); zi = 0; }
    const float* W = pa.W[set] + (long long)zi * 65536;
    unsigned short* H = pa.H[set] + (long long)zi * 65536;
    unsigned short* L = pa.Lo[set] + (long long)zi * 65536;

    __shared__ float tile[64][65];
    const int k0 = blockIdx.y * 64, n0 = blockIdx.x * 64;
    const int c = threadIdx.x & 63, r4 = threadIdx.x >> 6;

    #pragma unroll
    for (int i = 0; i < 16; ++i) {
        int kl = r4 + i * 4;
        tile[kl][c] = W[(long long)(k0 + kl) * 256 + n0 + c];
    }
    __syncthreads();
    #pragma unroll
    for (int i = 0; i < 16; ++i) {
        int nl = r4 + i * 4;
        float v = tile[c][nl];
        unsigned short hh = bf16_rn(v);
        unsigned short ll = bf16_rn(v - bf16_f(hh));
        long long o = (long long)(n0 + nl) * 256 + k0 + c;
        H[o] = hh;
        L[o] = ll;
    }
}

// ---------------------------------------------------------------------------
// Shared MFMA-GEMM macro body: bf16x3, 128x128 tile, 4 waves.
// Stages A/B hi+lo via global_load_lds(16B) with granule XOR swizzle.
// Leaves acc[4][4] (f32x4) ready for the caller-specific epilogue.
// ---------------------------------------------------------------------------
#define GEMM_BODY(aH, aL, bH, bL)                                                   \
    const int bm = blockIdx.y * 128;                                                \
    const int bn = blockIdx.x * 128;                                                \
    const int tid = threadIdx.x;                                                    \
    const int w = tid >> 6, l = tid & 63;                                           \
    const int wr = w >> 1, wc = w & 1;                                              \
    const int lr = l & 15, lk = l >> 4;                                             \
    __shared__ __align__(16) unsigned short lds[16384];                             \
    unsigned short* lAh = lds;                                                      \
    unsigned short* lAl = lds + 4096;                                               \
    unsigned short* lBh = lds + 8192;                                               \
    unsigned short* lBl = lds + 12288;                                              \
    const int g0 = w * 64 + l;                                                      \
    const int g1 = g0 + 256;                                                        \
    const int row0 = g0 >> 2, kq0 = (g0 & 3) ^ ((row0 >> 1) & 3);                   \
    const int row1 = g1 >> 2, kq1 = (g1 & 3) ^ ((row1 >> 1) & 3);                   \
    const long long offA0 = (long long)(bm + row0) * 512 + kq0 * 16;                \
    const long long offA1 = (long long)(bm + row1) * 512 + kq1 * 16;                \
    const long long offB0 = (long long)(bn + row0) * 512 + kq0 * 16;                \
    const long long offB1 = (long long)(bn + row1) * 512 + kq1 * 16;                \
    f32x4 acc[4][4];                                                                \
    _Pragma("unroll")                                                               \
    for (int m = 0; m < 4; ++m)                                                     \
        _Pragma("unroll")                                                           \
        for (int n = 0; n < 4; ++n)                                                 \
            acc[m][n] = (f32x4){0.f, 0.f, 0.f, 0.f};                                \
    for (int k0 = 0; k0 < 256; k0 += 32) {                                          \
        const long long kb = (long long)k0 * 2;                                     \
        __builtin_amdgcn_global_load_lds((const ASG unsigned int*)(aH + offA0 + kb),\
                                         (ASL unsigned int*)&lAh[g0 * 8], 16, 0, 0);\
        __builtin_amdgcn_global_load_lds((const ASG unsigned int*)(aH + offA1 + kb),\
                                         (ASL unsigned int*)&lAh[g1 * 8], 16, 0, 0);\
        __builtin_amdgcn_global_load_lds((const ASG unsigned int*)(aL + offA0 + kb),\
                                         (ASL unsigned int*)&lAl[g0 * 8], 16, 0, 0);\
        __builtin_amdgcn_global_load_lds((const ASG unsigned int*)(aL + offA1 + kb),\
                                         (ASL unsigned int*)&lAl[g1 * 8], 16, 0, 0);\
        __builtin_amdgcn_global_load_lds((const ASG unsigned int*)(bH + offB0 + kb),\
                                         (ASL unsigned int*)&lBh[g0 * 8], 16, 0, 0);\
        __builtin_amdgcn_global_load_lds((const ASG unsigned int*)(bH + offB1 + kb),\
                                         (ASL unsigned int*)&lBh[g1 * 8], 16, 0, 0);\
        __builtin_amdgcn_global_load_lds((const ASG unsigned int*)(bL + offB0 + kb),\
                                         (ASL unsigned int*)&lBl[g0 * 8], 16, 0, 0);\
        __builtin_amdgcn_global_load_lds((const ASG unsigned int*)(bL + offB1 + kb),\
                                         (ASL unsigned int*)&lBl[g1 * 8], 16, 0, 0);\
        asm volatile("s_waitcnt vmcnt(0)" ::: "memory");                            \
        __syncthreads();                                                            \
        short8 fah[4], fal[4], fbh[4], fbl[4];                                      \
        _Pragma("unroll")                                                           \
        for (int m = 0; m < 4; ++m) {                                               \
            int row = wr * 64 + m * 16 + lr;                                        \
            int off = row * 32 + ((lk ^ ((row >> 1) & 3)) * 8);                     \
            fah[m] = *(const short8*)&lAh[off];                                     \
            fal[m] = *(const short8*)&lAl[off];                                     \
        }                                                                           \
        _Pragma("unroll")                                                           \
        for (int n = 0; n < 4; ++n) {                                               \
            int row = wc * 64 + n * 16 + lr;                                        \
            int off = row * 32 + ((lk ^ ((row >> 1) & 3)) * 8);                     \
            fbh[n] = *(const short8*)&lBh[off];                                     \
            fbl[n] = *(const short8*)&lBl[off];                                     \
        }                                                                           \
        _Pragma("unroll")                                                           \
        for (int m = 0; m < 4; ++m)                                                 \
            _Pragma("unroll")                                                       \
            for (int n = 0; n < 4; ++n) {                                           \
                acc[m][n] = __builtin_amdgcn_mfma_f32_16x16x32_bf16(fah[m], fbh[n], acc[m][n], 0, 0, 0); \
                acc[m][n] = __builtin_amdgcn_mfma_f32_16x16x32_bf16(fal[m], fbh[n], acc[m][n], 0, 0, 0); \
                acc[m][n] = __builtin_amdgcn_mfma_f32_16x16x32_bf16(fah[m], fbl[n], acc[m][n], 0, 0, 0); \
            }                                                                       \
        __syncthreads();                                                            \
    }

// ---------------------------------------------------------------------------
// Fused Q/K/V projection. grid (2, M/128, 12): z = proj*NB + zb.
// Q,K -> bf16 rows (Q pre-scaled by SCALE*log2e); V -> VT layout
// [blkb][h][e][L] bf16 (transposed per head), absorbing v_transpose.
// ---------------------------------------------------------------------------
__global__ __launch_bounds__(256, 3) void gemm_qkv(
    const unsigned short* __restrict__ Ah, const unsigned short* __restrict__ Al,
    const unsigned short* __restrict__ Wbase,
    const float* __restrict__ bq, const float* __restrict__ bk, const float* __restrict__ bv,
    unsigned short* __restrict__ Qout, unsigned short* __restrict__ Kout,
    unsigned short* __restrict__ VTout,
    float qscale, int M, int kvShift)
{
    const int zAll = blockIdx.z;
    const int proj = zAll >> 2;
    const int zb   = zAll & 3;
    const long long sX = (long long)M * 256;
    const char* aH = (const char*)(Ah + zb * sX);
    const char* aL = (const char*)(Al + zb * sX);
    const long long wOff = (long long)proj * (2LL * NB * 65536) + (long long)zb * 65536;
    const char* bH = (const char*)(Wbase + wOff);
    const char* bL = (const char*)(Wbase + wOff + NB * 65536);
    const float* bz = (proj == 0 ? bq : proj == 1 ? bk : bv) + zb * 256;

    GEMM_BODY(aH, aL, bH, bL)

    if (proj < 2) {
        unsigned short* C = (proj == 0 ? Qout : Kout) + zb * sX;
        const float sc = (proj == 0) ? qscale : 1.0f;
        #pragma unroll
        for (int n = 0; n < 4; ++n) {
            const int col = bn + wc * 64 + n * 16 + lr;
            const float bv_ = bz[col];
            #pragma unroll
            for (int m = 0; m < 4; ++m) {
                const int row = bm + wr * 64 + m * 16 + lk * 4;
                #pragma unroll
                for (int j = 0; j < 4; ++j)
                    C[(long long)(row + j) * 256 + col] = bf16_rn((acc[m][n][j] + bv_) * sc);
            }
        }
    } else {
        const int Lkv = 1 << kvShift;
        #pragma unroll
        for (int n = 0; n < 4; ++n) {
            const int col = bn + wc * 64 + n * 16 + lr;
            const int hh = col >> 5, e = col & 31;
            const float bv_ = bz[col];
            #pragma unroll
            for (int m = 0; m < 4; ++m) {
                const int row = bm + wr * 64 + m * 16 + lk * 4;
                #pragma unroll
                for (int j = 0; j < 4; ++j) {
                    const int r = row + j;
                    const int blkb = zb * BATCH + (r >> kvShift);
                    const long long dst =
                        ((((long long)blkb * HEADS + hh) * 32 + e) << kvShift) + (r & (Lkv - 1));
                    VTout[dst] = bf16_rn(acc[m][n][j] + bv_);
                }
            }
        }
    }
}

// ---------------------------------------------------------------------------
// Generic bf16x3 GEMM, fp32 out. Per-z bias pointer passed by value.
// ---------------------------------------------------------------------------
struct Bias4 { const float* p[4]; };

__global__ __launch_bounds__(256, 3) void gemm_f32out(
    const unsigned short* __restrict__ Ah, const unsigned short* __restrict__ Al,
    const unsigned short* __restrict__ Bh_, const unsigned short* __restrict__ Bl_,
    Bias4 b4, float* __restrict__ C,
    long long sA, long long sW, long long sC)
{
    const int z = blockIdx.z;
    const char* aH = (const char*)(Ah + z * sA);
    const char* aL = (const char*)(Al + z * sA);
    const char* bH = (const char*)(Bh_ + z * sW);
    const char* bL = (const char*)(Bl_ + z * sW);
    const float* bz = b4.p[z];

    GEMM_BODY(aH, aL, bH, bL)

    #pragma unroll
    for (int n = 0; n < 4; ++n) {
        const int col = bn + wc * 64 + n * 16 + lr;
        const float bv_ = bz[col];
        #pragma unroll
        for (int m = 0; m < 4; ++m) {
            const int row = bm + wr * 64 + m * 16 + lk * 4;
            #pragma unroll
            for (int j = 0; j < 4; ++j)
                C[z * sC + (long long)(row + j) * 256 + col] = acc[m][n][j] + bv_;
        }
    }
}

// ---------------------------------------------------------------------------
// MFMA flash attention, fused S->P->PV per 32-kv step.
// LDS: K [L][32] swz + VT [32][L] swz + per-wave double-buffered P [16][32].
// L=256: 40 KiB -> 4 blocks/CU.  Q pre-scaled by SCALE*log2e at projection.
// ---------------------------------------------------------------------------
template<int L>
__global__ __launch_bounds__(256, 4) void attn_mfma(
    const unsigned short* __restrict__ Qbf, const unsigned short* __restrict__ Kbf,
    const unsigned short* __restrict__ VT,
    unsigned short* __restrict__ AOh, unsigned short* __restrict__ AOl)
{
    constexpr int QT_PER_WAVE = L / 64;
    constexpr int NS      = L / 32;
    constexpr int K_BYTES = L * 64;
    constexpr int GPR     = L / 8;         // 16B granules per VT row

    __shared__ __align__(16) char smem[2 * K_BYTES + 4 * 2048];
    unsigned short* Ks  = (unsigned short*)smem;                    // [L][32] swz
    unsigned short* VTs = (unsigned short*)(smem + K_BYTES);        // [32][L] swz
    unsigned short* Pa  = (unsigned short*)(smem + 2 * K_BYTES);    // 4w x 2 x [16][32]

    const int h    = blockIdx.x;
    const int blkb = blockIdx.y;
    const int tid  = threadIdx.x;
    const int w    = tid >> 6;
    const int l    = tid & 63;
    const int lq   = l & 15;
    const int lg   = l >> 4;
    const int a3   = (lq >> 2) & 3;

    const long long rowbase = (long long)blkb * L;
    const unsigned short* Kh = Kbf + rowbase * 256 + h * 32;
    const unsigned short* Qh = Qbf + rowbase * 256 + h * 32;
    const unsigned short* Vh = VT + ((long long)blkb * HEADS + h) * (32 * L);

    // prefetch Q fragments for all q-tiles of this wave (issues before waits)
    short8 qf[QT_PER_WAVE];
    #pragma unroll
    for (int qt = 0; qt < QT_PER_WAVE; ++qt) {
        int q0 = w * (QT_PER_WAVE * 16) + qt * 16;
        qf[qt] = *(const short8*)(Qh + (long long)(q0 + lq) * 256 + lg * 8);
    }

    // stage K: physical granule gi holds logical granule (gi&3)^((row>>1)&3)
    #pragma unroll
    for (int i = 0; i < K_BYTES / 16 / 256; ++i) {
        int gi = i * 256 + tid;
        int row = gi >> 2;
        int gsrc = (gi & 3) ^ ((row >> 1) & 3);
        __builtin_amdgcn_global_load_lds(
            (const ASG unsigned int*)(Kh + (long long)row * 256 + gsrc * 8),
            (ASL unsigned int*)(Ks + gi * 8), 16, 0, 0);
    }
    // stage VT: physical granule gp in row e holds logical gp^(e&7)
    #pragma unroll
    for (int i = 0; i < K_BYTES / 16 / 256; ++i) {
        int gi = i * 256 + tid;
        int e  = gi / GPR;
        int gsrc = (gi % GPR) ^ (e & 7);
        __builtin_amdgcn_global_load_lds(
            (const ASG unsigned int*)(Vh + (long long)e * L + gsrc * 8),
            (ASL unsigned int*)(VTs + gi * 8), 16, 0, 0);
    }
    asm volatile("s_waitcnt vmcnt(0)" ::: "memory");
    __syncthreads();

    unsigned short* Pw = Pa + w * 1024;     // 2 KiB / wave (double-buffered)

    #pragma unroll
    for (int qt = 0; qt < QT_PER_WAVE; ++qt) {
        const int q0 = w * (QT_PER_WAVE * 16) + qt * 16;
        f32x4 oacc[2] = {(f32x4){0.f,0.f,0.f,0.f}, (f32x4){0.f,0.f,0.f,0.f}};
        float lsum = 0.f;

        #pragma unroll
        for (int s = 0; s < NS; ++s) {
            unsigned short* Ps = Pw + (s & 1) * 512;
            // QK^T for the 32-kv window (two 16-row fragments)
            #pragma unroll
            for (int t2 = 0; t2 < 2; ++t2) {
                int row = s * 32 + t2 * 16 + lq;
                int off = row * 32 + ((lg ^ ((row >> 1) & 3)) * 8);
                short8 kf = *(const short8*)(Ks + off);
                f32x4 sf = __builtin_amdgcn_mfma_f32_16x16x32_bf16(
                               kf, qf[qt], (f32x4){0.f,0.f,0.f,0.f}, 0, 0, 0);
                float p0 = __builtin_exp2f(fminf(sf[0], 60.f));
                float p1 = __builtin_exp2f(fminf(sf[1], 60.f));
                float p2 = __builtin_exp2f(fminf(sf[2], 60.f));
                float p3 = __builtin_exp2f(fminf(sf[3], 60.f));
                lsum += (p0 + p1) + (p2 + p3);
                unsigned r0, r1;
                asm("v_cvt_pk_bf16_f32 %0, %1, %2" : "=v"(r0) : "v"(p0), "v"(p1));
                asm("v_cvt_pk_bf16_f32 %0, %1, %2" : "=v"(r1) : "v"(p2), "v"(p3));
                // P write: 8B slot, even-XOR swizzle keeps pair order
                int phys = (t2 * 4 + lg) ^ (a3 << 1);
                uint2 wv; wv.x = r0; wv.y = r1;
                *(uint2*)(Ps + lq * 32 + phys * 4) = wv;
            }
            asm volatile("s_waitcnt lgkmcnt(0)" ::: "memory");
            // P read: aligned 16B pair (logical slots 2lg, 2lg+1)
            int pair = (lg ^ a3) << 1;
            short8 pf = *(const short8*)(Ps + lq * 32 + pair * 4);
            #pragma unroll
            for (int et = 0; et < 2; ++et) {
                int e = et * 16 + lq;
                int gk = (s * 4 + lg) ^ (e & 7);
                short8 vf = *(const short8*)(VTs + e * L + gk * 8);
                oacc[et] = __builtin_amdgcn_mfma_f32_16x16x32_bf16(pf, vf, oacc[et], 0, 0, 0);
            }
        }

        lsum += __shfl_xor(lsum, 16);
        lsum += __shfl_xor(lsum, 32);
        float inv[4];
        #pragma unroll
        for (int j = 0; j < 4; ++j)
            inv[j] = 1.f / __shfl(lsum, lg * 4 + j);

        #pragma unroll
        for (int et = 0; et < 2; ++et)
            #pragma unroll
            for (int j = 0; j < 4; ++j) {
                long long row = rowbase + q0 + lg * 4 + j;
                int col = h * 32 + et * 16 + lq;
                float o = oacc[et][j] * inv[j];
                unsigned short hi = bf16_rn(o);
                unsigned short lo = bf16_rn(o - bf16_f(hi));
                AOh[row * 256 + col] = hi;
                AOl[row * 256 + col] = lo;
            }
    }
}

// ---------------------------------------------------------------------------
// Router gather + hi/lo split fused: RTh/RTl[b*4+i][d] = out[i][b][L-1][d]
// ---------------------------------------------------------------------------
__global__ void gather_split(const float* __restrict__ xi,
                             unsigned short* __restrict__ RTh,
                             unsigned short* __restrict__ RTl, int L)
{
    int t = blockIdx.x * blockDim.x + threadIdx.x;  // 0 .. 32767
    int d = t & 255;
    int r = t >> 8;
    int i = r & 3;
    int b = r >> 2;
    float v = xi[(((long long)i * BATCH + b) * L + (L - 1)) * DMODEL + d];
    unsigned short hh = bf16_rn(v);
    RTh[(long long)r * DMODEL + d] = hh;
    RTl[(long long)r * DMODEL + d] = bf16_rn(v - bf16_f(hh));
}

// ---------------------------------------------------------------------------
// Tiny inter attention over 4 router tokens; emits bf16 hi/lo directly.
// ---------------------------------------------------------------------------
__global__ void inter_attn(const float* __restrict__ RQ, const float* __restrict__ RK,
                           const float* __restrict__ RV,
                           unsigned short* __restrict__ RAh, unsigned short* __restrict__ RAl)
{
    const float SCALE_F = 0.17677669529663687f;
    int t = blockIdx.x * blockDim.x + threadIdx.x;  // 0 .. 1023
    int l = t & 3;
    int h = (t >> 2) & 7;
    int b = t >> 5;

    float q[EHEAD];
    #pragma unroll
    for (int e = 0; e < EHEAD; ++e)
        q[e] = RQ[((long long)b * 4 + l) * DMODEL + h * EHEAD + e];

    float sc[4];
    float m = -1e30f;
    #pragma unroll
    for (int s = 0; s < 4; ++s) {
        float d = 0.f;
        #pragma unroll
        for (int e = 0; e < EHEAD; ++e)
            d = fmaf(q[e], RK[((long long)b * 4 + s) * DMODEL + h * EHEAD + e], d);
        sc[s] = d * SCALE_F;
        m = fmaxf(m, sc[s]);
    }
    float lsum = 0.f;
    #pragma unroll
    for (int s = 0; s < 4; ++s) { sc[s] = __expf(sc[s] - m); lsum += sc[s]; }
    const float inv = 1.f / lsum;

    #pragma unroll
    for (int e = 0; e < EHEAD; ++e) {
        float a = 0.f;
        #pragma unroll
        for (int s = 0; s < 4; ++s)
            a = fmaf(sc[s], RV[((long long)b * 4 + s) * DMODEL + h * EHEAD + e], a);
        float o = a * inv;
        unsigned short hh = bf16_rn(o);
        RAh[((long long)b * 4 + l) * DMODEL + h * EHEAD + e] = hh;
        RAl[((long long)b * 4 + l) * DMODEL + h * EHEAD + e] = bf16_rn(o - bf16_f(hh));
    }
}

__global__ void scatter_routers(const float* __restrict__ ro, float* __restrict__ xi, int L)
{
    int t = blockIdx.x * blockDim.x + threadIdx.x;
    int d = t & 255;
    int r = t >> 8;
    int i = r & 3;
    int b = r >> 2;
    xi[(((long long)i * BATCH + b) * L + (L - 1)) * DMODEL + d] =
        ro[(long long)r * DMODEL + d];
}

// ---------------------------------------------------------------------------
struct BranchScratch {
    unsigned short *xh, *xl;
    unsigned short *Qbf, *Kbf, *VTb, *AOh, *AOl;
    unsigned short *Wth[4], *Wtl[4];
    unsigned short *WtIh[4], *WtIl[4];
    unsigned short *RTh, *RTl, *RAh, *RAl;
    float *RQKV, *RO;
};

template<int L>
static void run_branch(const float* x,
    const float* Wq, const float* bq, const float* Wk, const float* bk,
    const float* Wv, const float* bv, const float* Wo, const float* bo,
    const float* Wqi, const float* bqi, const float* Wki, const float* bki,
    const float* Wvi, const float* bvi, const float* Woi, const float* boi,
    float* out, const BranchScratch& S, hipStream_t stream)
{
    const int M = BATCH * L;
    const long long sX = (long long)M * DMODEL;
    const int nTot = NB * M * DMODEL;
    const int kvShift = (L == 256) ? 8 : 7;
    const float CS = 0.17677669529663687f * 1.4426950408889634f;  // SCALE*log2(e)

    split_hi_lo<<<1024, 256, 0, stream>>>(x, S.xh, S.xl, nTot / 4);

    PrepArgs pa;
    pa.W[0] = Wq;  pa.W[1] = Wk;  pa.W[2] = Wv;  pa.W[3] = Wo;
    pa.W[4] = Wqi; pa.W[5] = Wki; pa.W[6] = Wvi; pa.W[7] = Woi;
    for (int i = 0; i < 4; ++i) { pa.H[i] = S.Wth[i];  pa.Lo[i] = S.Wtl[i]; }
    for (int i = 0; i < 4; ++i) { pa.H[4+i] = S.WtIh[i]; pa.Lo[4+i] = S.WtIl[i]; }
    prep_weights<<<dim3(4, 4, 20), 256, 0, stream>>>(pa);

    gemm_qkv<<<dim3(2, M / 128, 12), 256, 0, stream>>>(
        S.xh, S.xl, S.Wth[0], bq, bk, bv, S.Qbf, S.Kbf, S.VTb, CS, M, kvShift);

    attn_mfma<L><<<dim3(HEADS, NB * BATCH), 256, 0, stream>>>(
        S.Qbf, S.Kbf, S.VTb, S.AOh, S.AOl);

    Bias4 b4o = {{bo, bo + 256, bo + 512, bo + 768}};
    gemm_f32out<<<dim3(2, M / 128, NB), 256, 0, stream>>>(
        S.AOh, S.AOl, S.Wth[3], S.Wtl[3], b4o, out, sX, 65536, sX);

    gather_split<<<128, 256, 0, stream>>>(out, S.RTh, S.RTl, L);

    Bias4 b4i = {{bqi, bki, bvi, nullptr}};
    gemm_f32out<<<dim3(2, 1, 3), 256, 0, stream>>>(
        S.RTh, S.RTl, S.WtIh[0], S.WtIl[0], b4i, S.RQKV, 0, 131072, 32768);

    inter_attn<<<4, 256, 0, stream>>>(S.RQKV, S.RQKV + 32768, S.RQKV + 65536,
                                      S.RAh, S.RAl);

    Bias4 b4r = {{boi, nullptr, nullptr, nullptr}};
    gemm_f32out<<<dim3(2, 1, 1), 256, 0, stream>>>(
        S.RAh, S.RAl, S.WtIh[3], S.WtIl[3], b4r, S.RO, 0, 0, 0);

    scatter_routers<<<128, 256, 0, stream>>>(S.RO, out, L);
}

// ---------------------------------------------------------------------------
extern "C" void kernel_launch(void* const* d_in, const int* in_sizes, int n_in,
                              void* d_out, int out_size, void* d_ws, size_t ws_size,
                              hipStream_t stream)
{
    const float* x_t  = (const float*)d_in[0];
    const float* x_c  = (const float*)d_in[1];
    const float* Wq_t = (const float*)d_in[2];  const float* bq_t = (const float*)d_in[3];
    const float* Wk_t = (const float*)d_in[4];  const float* bk_t = (const float*)d_in[5];
    const float* Wv_t = (const float*)d_in[6];  const float* bv_t = (const float*)d_in[7];
    const float* Wo_t = (const float*)d_in[8];  const float* bo_t = (const float*)d_in[9];
    const float* Wq_c = (const float*)d_in[10]; const float* bq_c = (const float*)d_in[11];
    const float* Wk_c = (const float*)d_in[12]; const float* bk_c = (const float*)d_in[13];
    const float* Wv_c = (const float*)d_in[14]; const float* bv_c = (const float*)d_in[15];
    const float* Wo_c = (const float*)d_in[16]; const float* bo_c = (const float*)d_in[17];
    const float* Wq_it = (const float*)d_in[18]; const float* bq_it = (const float*)d_in[19];
    const float* Wk_it = (const float*)d_in[20]; const float* bk_it = (const float*)d_in[21];
    const float* Wv_it = (const float*)d_in[22]; const float* bv_it = (const float*)d_in[23];
    const float* Wo_it = (const float*)d_in[24]; const float* bo_it = (const float*)d_in[25];
    const float* Wq_ic = (const float*)d_in[26]; const float* bq_ic = (const float*)d_in[27];
    const float* Wk_ic = (const float*)d_in[28]; const float* bk_ic = (const float*)d_in[29];
    const float* Wv_ic = (const float*)d_in[30]; const float* bv_ic = (const float*)d_in[31];
    const float* Wo_ic = (const float*)d_in[32]; const float* bo_ic = (const float*)d_in[33];

    float* out = (float*)d_out;

    char* p = (char*)d_ws;
    auto alloc = [&](size_t bytes) -> char* {
        char* r = p;
        p += (bytes + 255) & ~(size_t)255;
        return r;
    };
    const size_t QKV = (size_t)NB * BATCH * LT * DMODEL;   // 8,388,608 elements

    BranchScratch S;
    S.xh  = (unsigned short*)alloc(QKV * 2);
    S.xl  = (unsigned short*)alloc(QKV * 2);
    S.Qbf = (unsigned short*)alloc(QKV * 2);
    S.Kbf = (unsigned short*)alloc(QKV * 2);
    S.VTb = (unsigned short*)alloc(QKV * 2);
    S.AOh = (unsigned short*)alloc(QKV * 2);
    S.AOl = (unsigned short*)alloc(QKV * 2);
    // NOTE: Wth[i]/Wtl[i] must stay contiguous in this order (gemm_qkv indexes
    // proj*2*NB*65536 from Wth[0]); each alloc is a 256-multiple so no padding.
    for (int i = 0; i < 4; ++i) {
        S.Wth[i] = (unsigned short*)alloc((size_t)NB * 65536 * 2);
        S.Wtl[i] = (unsigned short*)alloc((size_t)NB * 65536 * 2);
    }
    for (int i = 0; i < 4; ++i) {
        S.WtIh[i] = (unsigned short*)alloc(65536 * 2);
        S.WtIl[i] = (unsigned short*)alloc(65536 * 2);
    }
    S.RTh  = (unsigned short*)alloc(128 * DMODEL * 2);
    S.RTl  = (unsigned short*)alloc(128 * DMODEL * 2);
    S.RAh  = (unsigned short*)alloc(128 * DMODEL * 2);
    S.RAl  = (unsigned short*)alloc(128 * DMODEL * 2);
    S.RQKV = (float*)alloc(3 * 128 * DMODEL * 4);
    S.RO   = (float*)alloc(128 * DMODEL * 4);

    run_branch<LT>(x_t, Wq_t, bq_t, Wk_t, bk_t, Wv_t, bv_t, Wo_t, bo_t,
                   Wq_it, bq_it, Wk_it, bk_it, Wv_it, bv_it, Wo_it, bo_it,
                   out, S, stream);

    float* out_c = out + (size_t)NB * BATCH * LT * DMODEL;
    run_branch<LC>(x_c, Wq_c, bq_c, Wk_c, bk_c, Wv_c, bv_c, Wo_c, bo_c,
                   Wq_ic, bq_ic, Wk_ic, bk_ic, Wv_ic, bv_ic, Wo_ic, bo_ic,
                   out_c, S, stream);
}